// Round 11
// baseline (454.176 us; speedup 1.0000x reference)
//
#include <hip/hip_runtime.h>
#include <math.h>

// WavelengthDependentPropagation: out = ifft2( fft2(x) * H(lam_c, fy, fx) )
// B=8, C=3, H=W=1024.  Panel-layout pipeline built from best-measured pieces.
//   P layout: [img:24][xt:128][y:1024][xi:8] complex (panel = 64KB contiguous)
//   K0: Htab[lam][kx][ky] (T orientation), pre-scaled by 2^-20
//   K1: 8 rows/block row FFT -> panel store (64B/lane-quad @64KB stride; R4 ~60us)
//   K2: barrier-free, wave-private: wave w of a panel-block owns column xi=w.
//       global->regs -> FFT -> *H -> iFFT -> store.  Twiddles computed once,
//       reused (negated) for the inverse FFT.
//       If big workspace: store T[img][x][y] (contiguous 8KB/wave) and
//       K3 = T16 full-line-gather variant (38us); else in-place panel + K3P.
//   K3: inverse row FFT -> output planes.

#define NIMG 24

__device__ __forceinline__ float2 cadd(float2 a, float2 b){ return make_float2(a.x+b.x, a.y+b.y); }
__device__ __forceinline__ float2 csub(float2 a, float2 b){ return make_float2(a.x-b.x, a.y-b.y); }
__device__ __forceinline__ float2 cmul(float2 a, float c, float s){ return make_float2(a.x*c - a.y*s, a.x*s + a.y*c); }

// swizzled byte offset within an 8KB column buffer for complex index j
__device__ __forceinline__ int SW(int j) {
    int b = j << 3;
    return b ^ (((b >> 7) & 7) << 4);
}
// same swizzle for an aligned complex PAIR (16B unit), a = j>>1
__device__ __forceinline__ int SW16(int a) {
    int b = a << 4;
    return b ^ (((b >> 7) & 7) << 4);
}

// ---------------- transfer function (mirrors the jnp fp32 chain exactly) ----
__device__ __forceinline__ float2 computeH(float lam, int ky, int kx) {
    int iy = (ky < 512) ? ky : ky - 1024;
    int ix = (kx < 512) ? kx : kx - 1024;
    const double recip = 1.0 / (1024.0 * 8e-06);
    float fy = (float)((double)iy * recip);
    float fx = (float)((double)ix * recip);
    float f2  = __fadd_rn(__fmul_rn(fy, fy), __fmul_rn(fx, fx));
    float l2  = __fmul_rn(lam, lam);
    float arg = __fsub_rn(1.0f, __fmul_rn(l2, f2));
    float2 h = make_float2(0.0f, 0.0f);
    if (arg > 0.0f) {
        float t  = __fdiv_rn(6.28318530717958647692f, lam);
        t        = __fmul_rn(t, 0.05f);
        float kz = __fmul_rn(t, __fsqrt_rn(arg));
        double s, c;
        sincos((double)kz, &s, &c);
        const float sc = 9.5367431640625e-07f;              // 2^-20
        h = make_float2((float)c * sc, (float)s * sc);
    }
    return h;
}

// Htab[c][kx][ky]  (T orientation: contiguous in ky)
__global__ __launch_bounds__(256) void build_H_T(float2* __restrict__ Htab,
                                                 const float* __restrict__ wl) {
    int idx = blockIdx.x * 256 + threadIdx.x;
    int c   = idx >> 20;
    int rem = idx & 1048575;
    Htab[idx] = computeH(wl[c], rem & 1023, rem >> 10);
}

// ---------------- radix-4 butterflies ---------------------------------------
template<int SIGN>
__device__ __forceinline__ void dft4nt(float2& a0, float2& a1, float2& a2, float2& a3) {
    float2 t0 = cadd(a0, a2), t1 = csub(a0, a2);
    float2 t2 = cadd(a1, a3), t3 = csub(a1, a3);
    a0 = cadd(t0, t2);
    a2 = csub(t0, t2);
    a1 = make_float2(t1.x - SIGN * t3.y, t1.y + SIGN * t3.x);
    a3 = make_float2(t1.x + SIGN * t3.y, t1.y - SIGN * t3.x);
}
template<int SIGN>
__device__ __forceinline__ void dft4(float2& a0, float2& a1, float2& a2, float2& a3,
                                     float c1, float s1) {
    float c2 = c1*c1 - s1*s1, s2 = 2.f*c1*s1;
    float c3 = c2*c1 - s2*s1, s3 = s2*c1 + c2*s1;
    a1 = cmul(a1, c1, s1);
    a2 = cmul(a2, c2, s2);
    a3 = cmul(a3, c3, s3);
    dft4nt<SIGN>(a0, a1, a2, a3);
}

#define WSYNC() do { asm volatile("s_waitcnt lgkmcnt(0)" ::: "memory"); \
                     __builtin_amdgcn_wave_barrier(); } while (0)

// ---------------- modular 1024-pt wave-private FFT pieces (verified R1-R10) --
// Register layout for round-A input and round-C output: v[a][b] = pos l+64(a+4b).

__device__ __forceinline__ void ldsToRegs(char* cb, int l, float2 (&v)[4][4]) {
    const int swzE = (((l >> 4)    ) & 7) << 4;
    const int swzO = (((l >> 4) + 4) & 7) << 4;
    char* rbE = cb + ((8 * l) ^ swzE);
    char* rbO = cb + ((8 * l) ^ swzO);
    #pragma unroll
    for (int k = 0; k < 4; ++k) {
        #pragma unroll
        for (int r = 0; r < 4; ++r) {
            const int tt = k + 4 * r;
            v[k][r] = *(const float2*)(((tt & 1) ? rbO : rbE) + 512 * tt);
        }
    }
}
__device__ __forceinline__ void regsToLds(char* cb, int l, const float2 (&v)[4][4]) {
    const int swzE = (((l >> 4)    ) & 7) << 4;
    const int swzO = (((l >> 4) + 4) & 7) << 4;
    char* rbE = cb + ((8 * l) ^ swzE);
    char* rbO = cb + ((8 * l) ^ swzO);
    #pragma unroll
    for (int m = 0; m < 4; ++m) {
        #pragma unroll
        for (int q = 0; q < 4; ++q) {
            const int tt = m + 4 * q;
            *(float2*)(((tt & 1) ? rbO : rbE) + 512 * tt) = v[m][q];
        }
    }
}

// Round A: stages 0+1 (twiddles are compile-time constants)
template<int SIGN>
__device__ __forceinline__ void fftA(char* cb, int l, float2 (&v)[4][4]) {
    #pragma unroll
    for (int k = 0; k < 4; ++k) dft4nt<SIGN>(v[k][0], v[k][1], v[k][2], v[k][3]);
    dft4nt<SIGN>(v[0][0], v[1][0], v[2][0], v[3][0]);
    dft4<SIGN>(v[0][1], v[1][1], v[2][1], v[3][1],
               0.92387953251128674f, SIGN * 0.38268343236508978f);
    dft4<SIGN>(v[0][2], v[1][2], v[2][2], v[3][2],
               0.70710678118654752f, SIGN * 0.70710678118654752f);
    dft4<SIGN>(v[0][3], v[1][3], v[2][3], v[3][3],
               0.38268343236508978f, SIGN * 0.92387953251128674f);
    char* wb = cb + 128 * l;
    const int L7 = l & 7;
    #pragma unroll
    for (int p = 0; p < 4; ++p) {
        *(float4*)(wb + 16 * ((2*p+0) ^ L7)) =
            make_float4(v[p][0].x, v[p][0].y, v[p][1].x, v[p][1].y);
        *(float4*)(wb + 16 * ((2*p+1) ^ L7)) =
            make_float4(v[p][2].x, v[p][2].y, v[p][3].x, v[p][3].y);
    }
}

// Round B with inline twiddles (K1/K3)
template<int SIGN>
__device__ __forceinline__ void fftB(char* cb, int l) {
    const float SPI32  = SIGN * 0.09817477042468103870f;   // pi/32
    const float SPI128 = SIGN * 0.02454369260617025967f;   // pi/128
    const int swzE = (((l >> 4)    ) & 7) << 4;
    const int swzO = (((l >> 4) + 4) & 7) << 4;
    char* rbE = cb + ((8 * l) ^ swzE);
    char* rbO = cb + ((8 * l) ^ swzO);
    float2 v[4][4];
    #pragma unroll
    for (int k = 0; k < 4; ++k) {
        #pragma unroll
        for (int r = 0; r < 4; ++r) {
            const int tt = k + 4 * r;
            v[k][r] = *(const float2*)(((tt & 1) ? rbO : rbE) + 512 * tt);
        }
    }
    const int jm2 = l & 15;
    float s1, c1; __sincosf((float)jm2 * SPI32, &s1, &c1);
    #pragma unroll
    for (int k = 0; k < 4; ++k) dft4<SIGN>(v[k][0], v[k][1], v[k][2], v[k][3], c1, s1);
    const int lo8 = 8 * (l & 15);
    const int hi  = 2048 * (l >> 4);
    #pragma unroll
    for (int q = 0; q < 4; ++q) {
        float s1b, c1b; __sincosf((float)(jm2 + 16 * q) * SPI128, &s1b, &c1b);
        dft4<SIGN>(v[0][q], v[1][q], v[2][q], v[3][q], c1b, s1b);
        #pragma unroll
        for (int p = 0; p < 4; ++p) {
            const int K = ((q + 4 * p) & 7) << 4;
            *(float2*)(cb + (lo8 ^ K) + hi + 128 * q + 512 * p) = v[p][q];
        }
    }
}

// Round B with precomputed twiddles (K2): cB,sB for jm2; cq,sq for jm2+16q
template<int SIGN>
__device__ __forceinline__ void fftB_tw(char* cb, int l, float cB, float sB,
                                        const float (&cq)[4], const float (&sq)[4]) {
    const int swzE = (((l >> 4)    ) & 7) << 4;
    const int swzO = (((l >> 4) + 4) & 7) << 4;
    char* rbE = cb + ((8 * l) ^ swzE);
    char* rbO = cb + ((8 * l) ^ swzO);
    float2 v[4][4];
    #pragma unroll
    for (int k = 0; k < 4; ++k) {
        #pragma unroll
        for (int r = 0; r < 4; ++r) {
            const int tt = k + 4 * r;
            v[k][r] = *(const float2*)(((tt & 1) ? rbO : rbE) + 512 * tt);
        }
    }
    const float s1 = SIGN * sB;
    #pragma unroll
    for (int k = 0; k < 4; ++k) dft4<SIGN>(v[k][0], v[k][1], v[k][2], v[k][3], cB, s1);
    const int lo8 = 8 * (l & 15);
    const int hi  = 2048 * (l >> 4);
    #pragma unroll
    for (int q = 0; q < 4; ++q) {
        dft4<SIGN>(v[0][q], v[1][q], v[2][q], v[3][q], cq[q], SIGN * sq[q]);
        #pragma unroll
        for (int p = 0; p < 4; ++p) {
            const int K = ((q + 4 * p) & 7) << 4;
            *(float2*)(cb + (lo8 ^ K) + hi + 128 * q + 512 * p) = v[p][q];
        }
    }
}

// Round C inline twiddles (K1/K3)
template<int SIGN>
__device__ __forceinline__ void fftC(int l, float2 (&v)[4][4]) {
    const float SPI512 = SIGN * 0.00613592315154256492f;   // pi/512
    #pragma unroll
    for (int m = 0; m < 4; ++m) {
        float s1, c1; __sincosf((float)(l + 64 * m) * SPI512, &s1, &c1);
        dft4<SIGN>(v[m][0], v[m][1], v[m][2], v[m][3], c1, s1);
    }
}
// Round C precomputed twiddles (K2)
template<int SIGN>
__device__ __forceinline__ void fftC_tw(float2 (&v)[4][4],
                                        const float (&cC)[4], const float (&sC)[4]) {
    #pragma unroll
    for (int m = 0; m < 4; ++m)
        dft4<SIGN>(v[m][0], v[m][1], v[m][2], v[m][3], cC[m], SIGN * sC[m]);
}

// ---------------- K1: row FFT -> panel store (R4-verified pattern) -----------
// 512 thr = 8 waves, 8 rows/block, 64KB LDS.
__global__ __launch_bounds__(512, 4) void k1_rows_P(const float* __restrict__ xr,
                                                    const float* __restrict__ xi,
                                                    float2* __restrict__ P) {
    __shared__ float4 ldsb[4096];                 // 64 KB
    char* lds = (char*)ldsb;
    const int t = threadIdx.x, w = t >> 6, l = t & 63;
    const int img = blockIdx.x >> 7;
    const int y0  = (blockIdx.x & 127) << 3;
    const long long ib = (long long)img << 20;
    char* cb = lds + 8192 * w;                    // wave w owns row y0+w

    // direct global->reg load, round-A layout (256B/instr coalesced)
    const float* rr = xr + ib + (long long)(y0 + w) * 1024;
    const float* ri = xi + ib + (long long)(y0 + w) * 1024;
    float2 v[4][4];
    #pragma unroll
    for (int k = 0; k < 4; ++k) {
        #pragma unroll
        for (int r = 0; r < 4; ++r) {
            const int p = l + 64 * (k + 4 * r);
            v[k][r] = make_float2(rr[p], ri[p]);
        }
    }
    fftA<-1>(cb, l, v); WSYNC();
    fftB<-1>(cb, l);    WSYNC();
    ldsToRegs(cb, l, v);
    fftC<-1>(l, v);
    WSYNC();
    regsToLds(cb, l, v);
    __syncthreads();

    // panel store: thread t, iter k: row y0+k, pair a = t (64B/lane-quad)
    {
        const int xt = t >> 2, c2 = t & 3;
        const int a  = xt * 4 + c2;
        #pragma unroll
        for (int k = 0; k < 8; ++k) {
            float4 vv = *(const float4*)(lds + 8192 * k + SW16(a));
            *(float4*)(P + ib + (long long)xt * 8192 + (y0 + k) * 8 + 2 * c2) = vv;
        }
    }
}

// ---------------- K2: barrier-free column pass on panel layout ---------------
// 512 thr = 8 waves = one panel; wave w owns column xi=w.  Twiddles reused.
// Tout != null: write T[img][x][y] (contiguous 8KB/wave); else in-place panel.
__global__ __launch_bounds__(512, 4) void k2_cols_P(float2* __restrict__ P,
                                                    float2* __restrict__ Tout,
                                                    const float2* __restrict__ Htab,
                                                    const float* __restrict__ wl) {
    __shared__ float4 ldsb[4096];                 // 64KB (8 waves x 8KB)
    char* lds = (char*)ldsb;
    const int t = threadIdx.x, w = t >> 6, l = t & 63;
    const int img = blockIdx.x >> 7;
    const int xt  = blockIdx.x & 127;
    const int x   = (xt << 3) + w;
    const int lamIdx = img % 3;
    char* cb = lds + 8192 * w;
    const long long ib = (long long)img << 20;
    float2* pcol = P + ib + (long long)xt * 8192 + w + 8 * l;   // + 512*tt

    // precompute twiddles (shared by fwd and inv FFT)
    const int jm2 = l & 15;
    float cB, sB; __sincosf((float)jm2 * 0.09817477042468103870f, &sB, &cB);
    float cq[4], sq[4], cC[4], sC[4];
    #pragma unroll
    for (int q = 0; q < 4; ++q)
        __sincosf((float)(jm2 + 16 * q) * 0.02454369260617025967f, &sq[q], &cq[q]);
    #pragma unroll
    for (int m = 0; m < 4; ++m)
        __sincosf((float)(l + 64 * m) * 0.00613592315154256492f, &sC[m], &cC[m]);

    // global -> regs, round-A layout (8B @64B stride; block covers all lines)
    float2 v[4][4];
    #pragma unroll
    for (int k = 0; k < 4; ++k) {
        #pragma unroll
        for (int r = 0; r < 4; ++r)
            v[k][r] = pcol[512 * (k + 4 * r)];
    }
    fftA<-1>(cb, l, v);                WSYNC();
    fftB_tw<-1>(cb, l, cB, sB, cq, sq); WSYNC();

    // H loads issued here (cover latency under round C)
    float2 h[4][4];
    if (Htab) {
        const float2* hrow = Htab + ((long long)lamIdx << 20) + ((long long)x << 10);
        #pragma unroll
        for (int m = 0; m < 4; ++m) {
            #pragma unroll
            for (int q = 0; q < 4; ++q)
                h[m][q] = hrow[l + 64 * (m + 4 * q)];
        }
    } else {
        const float lam = wl[lamIdx];
        #pragma unroll
        for (int m = 0; m < 4; ++m) {
            #pragma unroll
            for (int q = 0; q < 4; ++q)
                h[m][q] = computeH(lam, l + 64 * (m + 4 * q), x);
        }
    }

    ldsToRegs(cb, l, v);
    fftC_tw<-1>(v, cC, sC);

    // *H in registers
    #pragma unroll
    for (int m = 0; m < 4; ++m) {
        #pragma unroll
        for (int q = 0; q < 4; ++q) {
            float2 a = v[m][q], hh = h[m][q];
            v[m][q] = make_float2(a.x * hh.x - a.y * hh.y, a.x * hh.y + a.y * hh.x);
        }
    }
    WSYNC();   // order C-reads before inverse A-writes

    fftA<1>(cb, l, v);                 WSYNC();
    fftB_tw<1>(cb, l, cB, sB, cq, sq); WSYNC();
    ldsToRegs(cb, l, v);
    fftC_tw<1>(v, cC, sC);

    if (Tout) {
        float2* tcol = Tout + ib + ((long long)x << 10);   // contiguous per wave
        #pragma unroll
        for (int m = 0; m < 4; ++m) {
            #pragma unroll
            for (int q = 0; q < 4; ++q)
                tcol[l + 64 * (m + 4 * q)] = v[m][q];
        }
    } else {
        #pragma unroll
        for (int m = 0; m < 4; ++m) {
            #pragma unroll
            for (int q = 0; q < 4; ++q)
                pcol[512 * (m + 4 * q)] = v[m][q];
        }
    }
}

// ---------------- K3a: panel gather + inv row FFT -> planes (R4-verified) ----
__global__ __launch_bounds__(512, 4) void k3_irows_P(const float2* __restrict__ P,
                                                     float* __restrict__ outr,
                                                     float* __restrict__ outi) {
    __shared__ float4 ldsb[4096];                 // 64 KB
    char* lds = (char*)ldsb;
    const int t = threadIdx.x, w = t >> 6, l = t & 63;
    const int img = blockIdx.x >> 7;
    const int y0  = (blockIdx.x & 127) << 3;
    const long long ib = (long long)img << 20;
    char* cb = lds + 8192 * w;

    // panel gather (inverse of K1 store)
    {
        const int xt = t >> 2, c2 = t & 3;
        const int a  = xt * 4 + c2;
        #pragma unroll
        for (int k = 0; k < 8; ++k) {
            float4 g = *(const float4*)(P + ib + (long long)xt * 8192 + (y0 + k) * 8 + 2 * c2);
            *(float4*)(lds + 8192 * k + SW16(a)) = g;
        }
    }
    __syncthreads();

    float2 v[4][4];
    ldsToRegs(cb, l, v);
    fftA<1>(cb, l, v); WSYNC();
    fftB<1>(cb, l);    WSYNC();
    ldsToRegs(cb, l, v);
    fftC<1>(l, v);

    // direct store to planes (coalesced)
    float* pr = outr + ib + (long long)(y0 + w) * 1024;
    float* pi = outi + ib + (long long)(y0 + w) * 1024;
    #pragma unroll
    for (int m = 0; m < 4; ++m) {
        #pragma unroll
        for (int q = 0; q < 4; ++q) {
            const int p = l + 64 * (m + 4 * q);
            pr[p] = v[m][q].x;
            pi[p] = v[m][q].y;
        }
    }
}

// ---------------- K3b: T16 full-line gather variant (R8-verified, 38us) ------
__global__ __launch_bounds__(1024) void k3_irows_T16(const float2* __restrict__ T,
                                                     float* __restrict__ outr,
                                                     float* __restrict__ outi) {
    extern __shared__ char lds[];                 // 131072 bytes
    const int t = threadIdx.x, w = t >> 6, l = t & 63;
    const int img = blockIdx.x >> 6;
    const int y0  = (blockIdx.x & 63) << 4;
    const long long ib = (long long)img << 20;

    {
        const float4* src = (const float4*)(T + ib + ((long long)t << 10) + y0);
        const int sx = SW(t);
        #pragma unroll
        for (int p = 0; p < 8; ++p) {
            float4 g = src[p];
            *(float2*)(lds + 8192 * (2 * p)     + sx) = make_float2(g.x, g.y);
            *(float2*)(lds + 8192 * (2 * p + 1) + sx) = make_float2(g.z, g.w);
        }
    }
    __syncthreads();

    char* cb = lds + 8192 * w;                    // wave w owns row y0+w
    float2 v[4][4];
    ldsToRegs(cb, l, v);
    fftA<1>(cb, l, v); WSYNC();
    fftB<1>(cb, l);    WSYNC();
    ldsToRegs(cb, l, v);
    fftC<1>(l, v);

    float* pr = outr + ib + (long long)(y0 + w) * 1024;
    float* pi = outi + ib + (long long)(y0 + w) * 1024;
    #pragma unroll
    for (int m = 0; m < 4; ++m) {
        #pragma unroll
        for (int q = 0; q < 4; ++q) {
            const int p = l + 64 * (m + 4 * q);
            pr[p] = v[m][q].x;
            pi[p] = v[m][q].y;
        }
    }
}

// ---------------- launch ------------------------------------------------------
extern "C" void kernel_launch(void* const* d_in, const int* in_sizes, int n_in,
                              void* d_out, int out_size, void* d_ws, size_t ws_size,
                              hipStream_t stream) {
    const float* xr = (const float*)d_in[0];
    const float* xi = (const float*)d_in[1];
    const float* wl = (const float*)d_in[2];
    float* out = (float*)d_out;

    const size_t planeElems = (size_t)NIMG * 1024 * 1024;          // 24M complex
    const size_t needP = planeElems * sizeof(float2);              // 192 MB
    const size_t needT = needP;                                    // 192 MB
    const size_t needH = (size_t)3 * 1024 * 1024 * sizeof(float2); // 24 MB

    float2* P = (float2*)d_ws;
    float2* T = nullptr;
    float2* Htab = nullptr;

    if (ws_size >= needP + needT + needH) {
        T    = (float2*)((char*)d_ws + needP);
        Htab = (float2*)((char*)d_ws + needP + needT);
        build_H_T<<<12288, 256, 0, stream>>>(Htab, wl);
    } else if (ws_size >= needP + needH) {
        Htab = (float2*)((char*)d_ws + needP);
        build_H_T<<<12288, 256, 0, stream>>>(Htab, wl);
    }

    k1_rows_P<<<NIMG * 128, 512, 0, stream>>>(xr, xi, P);
    k2_cols_P<<<NIMG * 128, 512, 0, stream>>>(P, T, Htab, wl);
    if (T) {
        k3_irows_T16<<<NIMG * 64, 1024, 131072, stream>>>(T, out, out + planeElems);
    } else {
        k3_irows_P<<<NIMG * 128, 512, 0, stream>>>(P, out, out + planeElems);
    }
}

// Round 12
// 397.908 us; speedup vs baseline: 1.1414x; 1.1414x over previous
//
#include <hip/hip_runtime.h>
#include <math.h>

// WavelengthDependentPropagation: out = ifft2( fft2(x) * H(lam_c, fy, fx) )
// B=8, C=3, H=W=1024.  Panel-layout pipeline (R4 structure), K2 rebuilt:
//   P layout: [img:24][xt:128][y:1024][xi:8] complex (panel = 64KB contiguous)
//   K0: Htab[lam][kx][ky] (T orientation), pre-scaled by 2^-20
//   K1: 8 rows/block row FFT -> panel store (contiguous per instr; R4 ~60us)
//   K2: staged contiguous panel load -> ONE barrier -> wave-private
//       fwd FFT -> *H in registers -> inv FFT (twiddles computed once,
//       sign-flipped for inverse) -> ONE barrier -> staged contiguous store.
//   K3: panel gather -> inv row FFT -> output planes (R4 ~58us)
// Rule enforced everywhere (R2-R11 evidence): every global wave-instruction
// covers a contiguous >=512B span; no per-lane strided global access.

#define NIMG 24

__device__ __forceinline__ float2 cadd(float2 a, float2 b){ return make_float2(a.x+b.x, a.y+b.y); }
__device__ __forceinline__ float2 csub(float2 a, float2 b){ return make_float2(a.x-b.x, a.y-b.y); }
__device__ __forceinline__ float2 cmul(float2 a, float c, float s){ return make_float2(a.x*c - a.y*s, a.x*s + a.y*c); }

// swizzled byte offset within an 8KB column buffer for complex index j
__device__ __forceinline__ int SW(int j) {
    int b = j << 3;
    return b ^ (((b >> 7) & 7) << 4);
}
// same swizzle for an aligned complex PAIR (16B unit), a = j>>1
__device__ __forceinline__ int SW16(int a) {
    int b = a << 4;
    return b ^ (((b >> 7) & 7) << 4);
}

// ---------------- transfer function (mirrors the jnp fp32 chain exactly) ----
__device__ __forceinline__ float2 computeH(float lam, int ky, int kx) {
    int iy = (ky < 512) ? ky : ky - 1024;
    int ix = (kx < 512) ? kx : kx - 1024;
    const double recip = 1.0 / (1024.0 * 8e-06);
    float fy = (float)((double)iy * recip);
    float fx = (float)((double)ix * recip);
    float f2  = __fadd_rn(__fmul_rn(fy, fy), __fmul_rn(fx, fx));
    float l2  = __fmul_rn(lam, lam);
    float arg = __fsub_rn(1.0f, __fmul_rn(l2, f2));
    float2 h = make_float2(0.0f, 0.0f);
    if (arg > 0.0f) {
        float t  = __fdiv_rn(6.28318530717958647692f, lam);
        t        = __fmul_rn(t, 0.05f);
        float kz = __fmul_rn(t, __fsqrt_rn(arg));
        double s, c;
        sincos((double)kz, &s, &c);
        const float sc = 9.5367431640625e-07f;              // 2^-20
        h = make_float2((float)c * sc, (float)s * sc);
    }
    return h;
}

// Htab[c][kx][ky]  (T orientation: contiguous in ky)
__global__ __launch_bounds__(256) void build_H_T(float2* __restrict__ Htab,
                                                 const float* __restrict__ wl) {
    int idx = blockIdx.x * 256 + threadIdx.x;
    int c   = idx >> 20;
    int rem = idx & 1048575;
    Htab[idx] = computeH(wl[c], rem & 1023, rem >> 10);
}

// ---------------- radix-4 butterflies ---------------------------------------
template<int SIGN>
__device__ __forceinline__ void dft4nt(float2& a0, float2& a1, float2& a2, float2& a3) {
    float2 t0 = cadd(a0, a2), t1 = csub(a0, a2);
    float2 t2 = cadd(a1, a3), t3 = csub(a1, a3);
    a0 = cadd(t0, t2);
    a2 = csub(t0, t2);
    a1 = make_float2(t1.x - SIGN * t3.y, t1.y + SIGN * t3.x);
    a3 = make_float2(t1.x + SIGN * t3.y, t1.y - SIGN * t3.x);
}
template<int SIGN>
__device__ __forceinline__ void dft4(float2& a0, float2& a1, float2& a2, float2& a3,
                                     float c1, float s1) {
    float c2 = c1*c1 - s1*s1, s2 = 2.f*c1*s1;
    float c3 = c2*c1 - s2*s1, s3 = s2*c1 + c2*s1;
    a1 = cmul(a1, c1, s1);
    a2 = cmul(a2, c2, s2);
    a3 = cmul(a3, c3, s3);
    dft4nt<SIGN>(a0, a1, a2, a3);
}

#define WSYNC() do { asm volatile("s_waitcnt lgkmcnt(0)" ::: "memory"); \
                     __builtin_amdgcn_wave_barrier(); } while (0)

// ---------------- modular 1024-pt wave-private FFT pieces (verified R1-R11) --
// Register layout for round-A input and round-C output: v[a][b] = pos l+64(a+4b).

__device__ __forceinline__ void ldsToRegs(char* cb, int l, float2 (&v)[4][4]) {
    const int swzE = (((l >> 4)    ) & 7) << 4;
    const int swzO = (((l >> 4) + 4) & 7) << 4;
    char* rbE = cb + ((8 * l) ^ swzE);
    char* rbO = cb + ((8 * l) ^ swzO);
    #pragma unroll
    for (int k = 0; k < 4; ++k) {
        #pragma unroll
        for (int r = 0; r < 4; ++r) {
            const int tt = k + 4 * r;
            v[k][r] = *(const float2*)(((tt & 1) ? rbO : rbE) + 512 * tt);
        }
    }
}
__device__ __forceinline__ void regsToLds(char* cb, int l, const float2 (&v)[4][4]) {
    const int swzE = (((l >> 4)    ) & 7) << 4;
    const int swzO = (((l >> 4) + 4) & 7) << 4;
    char* rbE = cb + ((8 * l) ^ swzE);
    char* rbO = cb + ((8 * l) ^ swzO);
    #pragma unroll
    for (int m = 0; m < 4; ++m) {
        #pragma unroll
        for (int q = 0; q < 4; ++q) {
            const int tt = m + 4 * q;
            *(float2*)(((tt & 1) ? rbO : rbE) + 512 * tt) = v[m][q];
        }
    }
}

// Round A: stages 0+1 (compile-time twiddles)
template<int SIGN>
__device__ __forceinline__ void fftA(char* cb, int l, float2 (&v)[4][4]) {
    #pragma unroll
    for (int k = 0; k < 4; ++k) dft4nt<SIGN>(v[k][0], v[k][1], v[k][2], v[k][3]);
    dft4nt<SIGN>(v[0][0], v[1][0], v[2][0], v[3][0]);
    dft4<SIGN>(v[0][1], v[1][1], v[2][1], v[3][1],
               0.92387953251128674f, SIGN * 0.38268343236508978f);
    dft4<SIGN>(v[0][2], v[1][2], v[2][2], v[3][2],
               0.70710678118654752f, SIGN * 0.70710678118654752f);
    dft4<SIGN>(v[0][3], v[1][3], v[2][3], v[3][3],
               0.38268343236508978f, SIGN * 0.92387953251128674f);
    char* wb = cb + 128 * l;
    const int L7 = l & 7;
    #pragma unroll
    for (int p = 0; p < 4; ++p) {
        *(float4*)(wb + 16 * ((2*p+0) ^ L7)) =
            make_float4(v[p][0].x, v[p][0].y, v[p][1].x, v[p][1].y);
        *(float4*)(wb + 16 * ((2*p+1) ^ L7)) =
            make_float4(v[p][2].x, v[p][2].y, v[p][3].x, v[p][3].y);
    }
}

// Round B with inline twiddles (K1/K3)
template<int SIGN>
__device__ __forceinline__ void fftB(char* cb, int l) {
    const float SPI32  = SIGN * 0.09817477042468103870f;   // pi/32
    const float SPI128 = SIGN * 0.02454369260617025967f;   // pi/128
    const int swzE = (((l >> 4)    ) & 7) << 4;
    const int swzO = (((l >> 4) + 4) & 7) << 4;
    char* rbE = cb + ((8 * l) ^ swzE);
    char* rbO = cb + ((8 * l) ^ swzO);
    float2 v[4][4];
    #pragma unroll
    for (int k = 0; k < 4; ++k) {
        #pragma unroll
        for (int r = 0; r < 4; ++r) {
            const int tt = k + 4 * r;
            v[k][r] = *(const float2*)(((tt & 1) ? rbO : rbE) + 512 * tt);
        }
    }
    const int jm2 = l & 15;
    float s1, c1; __sincosf((float)jm2 * SPI32, &s1, &c1);
    #pragma unroll
    for (int k = 0; k < 4; ++k) dft4<SIGN>(v[k][0], v[k][1], v[k][2], v[k][3], c1, s1);
    const int lo8 = 8 * (l & 15);
    const int hi  = 2048 * (l >> 4);
    #pragma unroll
    for (int q = 0; q < 4; ++q) {
        float s1b, c1b; __sincosf((float)(jm2 + 16 * q) * SPI128, &s1b, &c1b);
        dft4<SIGN>(v[0][q], v[1][q], v[2][q], v[3][q], c1b, s1b);
        #pragma unroll
        for (int p = 0; p < 4; ++p) {
            const int K = ((q + 4 * p) & 7) << 4;
            *(float2*)(cb + (lo8 ^ K) + hi + 128 * q + 512 * p) = v[p][q];
        }
    }
}

// Round B with precomputed twiddles (K2)
template<int SIGN>
__device__ __forceinline__ void fftB_tw(char* cb, int l, float cB, float sB,
                                        const float (&cq)[4], const float (&sq)[4]) {
    const int swzE = (((l >> 4)    ) & 7) << 4;
    const int swzO = (((l >> 4) + 4) & 7) << 4;
    char* rbE = cb + ((8 * l) ^ swzE);
    char* rbO = cb + ((8 * l) ^ swzO);
    float2 v[4][4];
    #pragma unroll
    for (int k = 0; k < 4; ++k) {
        #pragma unroll
        for (int r = 0; r < 4; ++r) {
            const int tt = k + 4 * r;
            v[k][r] = *(const float2*)(((tt & 1) ? rbO : rbE) + 512 * tt);
        }
    }
    const float s1 = SIGN * sB;
    #pragma unroll
    for (int k = 0; k < 4; ++k) dft4<SIGN>(v[k][0], v[k][1], v[k][2], v[k][3], cB, s1);
    const int lo8 = 8 * (l & 15);
    const int hi  = 2048 * (l >> 4);
    #pragma unroll
    for (int q = 0; q < 4; ++q) {
        dft4<SIGN>(v[0][q], v[1][q], v[2][q], v[3][q], cq[q], SIGN * sq[q]);
        #pragma unroll
        for (int p = 0; p < 4; ++p) {
            const int K = ((q + 4 * p) & 7) << 4;
            *(float2*)(cb + (lo8 ^ K) + hi + 128 * q + 512 * p) = v[p][q];
        }
    }
}

// Round C inline twiddles (K1/K3)
template<int SIGN>
__device__ __forceinline__ void fftC(int l, float2 (&v)[4][4]) {
    const float SPI512 = SIGN * 0.00613592315154256492f;   // pi/512
    #pragma unroll
    for (int m = 0; m < 4; ++m) {
        float s1, c1; __sincosf((float)(l + 64 * m) * SPI512, &s1, &c1);
        dft4<SIGN>(v[m][0], v[m][1], v[m][2], v[m][3], c1, s1);
    }
}
// Round C precomputed twiddles (K2)
template<int SIGN>
__device__ __forceinline__ void fftC_tw(float2 (&v)[4][4],
                                        const float (&cC)[4], const float (&sC)[4]) {
    #pragma unroll
    for (int m = 0; m < 4; ++m)
        dft4<SIGN>(v[m][0], v[m][1], v[m][2], v[m][3], cC[m], SIGN * sC[m]);
}

// ---------------- K1: row FFT -> panel store (R4-verified) -------------------
__global__ __launch_bounds__(512, 4) void k1_rows_P(const float* __restrict__ xr,
                                                    const float* __restrict__ xi,
                                                    float2* __restrict__ P) {
    __shared__ float4 ldsb[4096];                 // 64 KB
    char* lds = (char*)ldsb;
    const int t = threadIdx.x, w = t >> 6, l = t & 63;
    const int img = blockIdx.x >> 7;
    const int y0  = (blockIdx.x & 127) << 3;
    const long long ib = (long long)img << 20;
    char* cb = lds + 8192 * w;                    // wave w owns row y0+w

    const float* rr = xr + ib + (long long)(y0 + w) * 1024;
    const float* ri = xi + ib + (long long)(y0 + w) * 1024;
    float2 v[4][4];
    #pragma unroll
    for (int k = 0; k < 4; ++k) {
        #pragma unroll
        for (int r = 0; r < 4; ++r) {
            const int p = l + 64 * (k + 4 * r);
            v[k][r] = make_float2(rr[p], ri[p]);
        }
    }
    fftA<-1>(cb, l, v); WSYNC();
    fftB<-1>(cb, l);    WSYNC();
    ldsToRegs(cb, l, v);
    fftC<-1>(l, v);
    WSYNC();
    regsToLds(cb, l, v);
    __syncthreads();

    // panel store: contiguous 64B per lane-quad, full panel covered by block
    {
        const int xt = t >> 2, c2 = t & 3;
        const int a  = xt * 4 + c2;
        #pragma unroll
        for (int k = 0; k < 8; ++k) {
            float4 vv = *(const float4*)(lds + 8192 * k + SW16(a));
            *(float4*)(P + ib + (long long)xt * 8192 + (y0 + k) * 8 + 2 * c2) = vv;
        }
    }
}

// ---------------- K2: staged panel I/O + wave-private register FFT core ------
// 512 thr = 8 waves = one panel.  TWO block barriers total.
__global__ __launch_bounds__(512, 4) void k2_cols_P(float2* __restrict__ P,
                                                    const float2* __restrict__ Htab,
                                                    const float* __restrict__ wl) {
    __shared__ float4 ldsb[4096];                 // 64KB
    char* lds = (char*)ldsb;
    const int t = threadIdx.x, w = t >> 6, l = t & 63;
    const int img = blockIdx.x >> 7;
    const int xt  = blockIdx.x & 127;
    const int x   = (xt << 3) + w;                // column owned by wave w
    const int lamIdx = img % 3;
    const long long ib = (long long)img << 20;
    float2* panel = P + ib + (long long)xt * 8192;
    char* cb = lds + 8192 * w;

    // --- staged load (R4-verified): contiguous float4 per instruction -------
    {
        const int c2 = t & 3, row = t >> 2;
        char* io0 = lds + 16384 * c2 + SW(row);   // col 2c2
        char* io1 = io0 + 8192;                   // col 2c2+1
        #pragma unroll
        for (int k = 0; k < 8; ++k) {
            float4 g = ((const float4*)panel)[512 * k + t];
            *(float2*)(io0 + 1024 * k) = make_float2(g.x, g.y);
            *(float2*)(io1 + 1024 * k) = make_float2(g.z, g.w);
        }
    }
    __syncthreads();                              // barrier 1

    // --- twiddles once (shared fwd/inv) -------------------------------------
    const int jm2 = l & 15;
    float cB, sB; __sincosf((float)jm2 * 0.09817477042468103870f, &sB, &cB);
    float cq[4], sq[4], cC[4], sC[4];
    #pragma unroll
    for (int q = 0; q < 4; ++q)
        __sincosf((float)(jm2 + 16 * q) * 0.02454369260617025967f, &sq[q], &cq[q]);
    #pragma unroll
    for (int m = 0; m < 4; ++m)
        __sincosf((float)(l + 64 * m) * 0.00613592315154256492f, &sC[m], &cC[m]);

    // --- forward FFT on wave-private column ---------------------------------
    float2 v[4][4];
    ldsToRegs(cb, l, v);
    fftA<-1>(cb, l, v);                 WSYNC();
    fftB_tw<-1>(cb, l, cB, sB, cq, sq); WSYNC();

    // H loads issued here (contiguous 512B/instr), consumed after round C
    float2 h[4][4];
    if (Htab) {
        const float2* hrow = Htab + ((long long)lamIdx << 20) + ((long long)x << 10);
        #pragma unroll
        for (int m = 0; m < 4; ++m) {
            #pragma unroll
            for (int q = 0; q < 4; ++q)
                h[m][q] = hrow[l + 64 * (m + 4 * q)];
        }
    } else {
        const float lam = wl[lamIdx];
        #pragma unroll
        for (int m = 0; m < 4; ++m) {
            #pragma unroll
            for (int q = 0; q < 4; ++q)
                h[m][q] = computeH(lam, l + 64 * (m + 4 * q), x);
        }
    }

    ldsToRegs(cb, l, v);
    fftC_tw<-1>(v, cC, sC);

    // --- *H in registers ----------------------------------------------------
    #pragma unroll
    for (int m = 0; m < 4; ++m) {
        #pragma unroll
        for (int q = 0; q < 4; ++q) {
            float2 a = v[m][q], hh = h[m][q];
            v[m][q] = make_float2(a.x * hh.x - a.y * hh.y, a.x * hh.y + a.y * hh.x);
        }
    }
    WSYNC();   // round-C LDS reads complete before inverse round-A writes

    // --- inverse FFT on the same private column -----------------------------
    fftA<1>(cb, l, v);                 WSYNC();
    fftB_tw<1>(cb, l, cB, sB, cq, sq); WSYNC();
    ldsToRegs(cb, l, v);
    fftC_tw<1>(v, cC, sC);
    WSYNC();
    regsToLds(cb, l, v);
    __syncthreads();                              // barrier 2

    // --- staged store (R4-verified): contiguous float4 per instruction ------
    {
        const int c2 = t & 3, row = t >> 2;
        char* io0 = lds + 16384 * c2 + SW(row);
        char* io1 = io0 + 8192;
        #pragma unroll
        for (int k = 0; k < 8; ++k) {
            float2 a = *(const float2*)(io0 + 1024 * k);
            float2 b = *(const float2*)(io1 + 1024 * k);
            ((float4*)panel)[512 * k + t] = make_float4(a.x, a.y, b.x, b.y);
        }
    }
}

// ---------------- K3: panel gather + inv row FFT -> planes (R4-verified) -----
__global__ __launch_bounds__(512, 4) void k3_irows_P(const float2* __restrict__ P,
                                                     float* __restrict__ outr,
                                                     float* __restrict__ outi) {
    __shared__ float4 ldsb[4096];                 // 64 KB
    char* lds = (char*)ldsb;
    const int t = threadIdx.x, w = t >> 6, l = t & 63;
    const int img = blockIdx.x >> 7;
    const int y0  = (blockIdx.x & 127) << 3;
    const long long ib = (long long)img << 20;
    char* cb = lds + 8192 * w;

    // panel gather (inverse of K1 store)
    {
        const int xt = t >> 2, c2 = t & 3;
        const int a  = xt * 4 + c2;
        #pragma unroll
        for (int k = 0; k < 8; ++k) {
            float4 g = *(const float4*)(P + ib + (long long)xt * 8192 + (y0 + k) * 8 + 2 * c2);
            *(float4*)(lds + 8192 * k + SW16(a)) = g;
        }
    }
    __syncthreads();

    float2 v[4][4];
    ldsToRegs(cb, l, v);
    fftA<1>(cb, l, v); WSYNC();
    fftB<1>(cb, l);    WSYNC();
    ldsToRegs(cb, l, v);
    fftC<1>(l, v);

    // direct store to planes (coalesced)
    float* pr = outr + ib + (long long)(y0 + w) * 1024;
    float* pi = outi + ib + (long long)(y0 + w) * 1024;
    #pragma unroll
    for (int m = 0; m < 4; ++m) {
        #pragma unroll
        for (int q = 0; q < 4; ++q) {
            const int p = l + 64 * (m + 4 * q);
            pr[p] = v[m][q].x;
            pi[p] = v[m][q].y;
        }
    }
}

// ---------------- launch ------------------------------------------------------
extern "C" void kernel_launch(void* const* d_in, const int* in_sizes, int n_in,
                              void* d_out, int out_size, void* d_ws, size_t ws_size,
                              hipStream_t stream) {
    const float* xr = (const float*)d_in[0];
    const float* xi = (const float*)d_in[1];
    const float* wl = (const float*)d_in[2];
    float* out = (float*)d_out;

    const size_t planeElems = (size_t)NIMG * 1024 * 1024;          // 24M complex
    const size_t needP = planeElems * sizeof(float2);              // 192 MB
    const size_t needH = (size_t)3 * 1024 * 1024 * sizeof(float2); // 24 MB

    float2* P = (float2*)d_ws;
    float2* Htab = nullptr;
    if (ws_size >= needP + needH) {
        Htab = (float2*)((char*)d_ws + needP);
        build_H_T<<<12288, 256, 0, stream>>>(Htab, wl);
    }

    k1_rows_P<<<NIMG * 128, 512, 0, stream>>>(xr, xi, P);
    k2_cols_P<<<NIMG * 128, 512, 0, stream>>>(P, Htab, wl);
    k3_irows_P<<<NIMG * 128, 512, 0, stream>>>(P, out, out + planeElems);
}